// Round 10
// baseline (1582.957 us; speedup 1.0000x reference)
//
#include <hip/hip_runtime.h>
#include <hip/hip_bf16.h>
#include <stdint.h>

// B=16, C=1024, D=H=W=8 -> N=512 tokens, 27 taps
#define BATCH 16
#define CCH   1024
#define NTOK  512
#define NKT   432   // K-tiles: 27 taps * (1024/64)

typedef _Float16 f16_t;
typedef f16_t f16x8 __attribute__((ext_vector_type(8)));
typedef f16_t f16x4 __attribute__((ext_vector_type(4)));
typedef float f32x4 __attribute__((ext_vector_type(4)));
typedef float f32x16 __attribute__((ext_vector_type(16)));

#define GAS __attribute__((address_space(1)))
#define LAS __attribute__((address_space(3)))

__device__ __forceinline__ void gload_lds16(const void* g, void* l) {
  __builtin_amdgcn_global_load_lds((const GAS uint32_t*)g, (LAS uint32_t*)l, 16, 0, 0);
}

// ---------------- cast + transpose: [B][C][N] f32 -> [B][N][C] f16 -----------
__global__ __launch_bounds__(256) void cast_transpose_kernel(
    const float* __restrict__ src, f16_t* __restrict__ dst) {
  __shared__ float tile[64][65];
  const int b  = blockIdx.z;
  const int c0 = blockIdx.y * 64;
  const int n0 = blockIdx.x * 64;
  const int col  = threadIdx.x & 63;
  const int row4 = threadIdx.x >> 6;
  const float* s = src + ((size_t)b * CCH + c0) * NTOK + n0;
#pragma unroll
  for (int r = 0; r < 64; r += 4)
    tile[r + row4][col] = s[(size_t)(r + row4) * NTOK + col];
  __syncthreads();
  f16_t* d = dst + ((size_t)b * NTOK + n0) * CCH + c0;
#pragma unroll
  for (int r = 0; r < 64; r += 4)
    d[(size_t)(r + row4) * CCH + col] = (f16_t)tile[col][r + row4];
}

// -------- weight transpose: [O][I][27] f32 -> rows o_base+o of [27][Mtot][1024]
__global__ __launch_bounds__(256) void wtrans_kernel(
    const float* __restrict__ w, f16_t* __restrict__ wt, const int o_base,
    const int Mtot) {
  __shared__ float buf[64 * 27];
  const int o  = blockIdx.x;
  const int i0 = blockIdx.y * 64;
  const float* s = w + (size_t)o * (CCH * 27) + (size_t)i0 * 27;
  for (int idx = threadIdx.x; idx < 64 * 27; idx += 256) buf[idx] = s[idx];
  __syncthreads();
  for (int idx = threadIdx.x; idx < 64 * 27; idx += 256) {
    const int t = idx >> 6;
    const int i = idx & 63;
    wt[((size_t)t * Mtot + o_base + o) * 1024 + i0 + i] = (f16_t)buf[i * 27 + t];
  }
}

// ================= conv K+V fused: M=2048, tile 256x256, BK=64 ===============
// R6 schedule verbatim (256 blocks, 8 waves 2Mx4N, 4-half 32KB ring, counted
// vmcnt(8), source-side slot swizzle) with MFMA shape 32x32x16 (higher rate,
// half the instruction count). Wave tile 128x64 = 4x2 tiles of 32x32,
// acc[4][2] f32x16 = 128 VGPR. A/B frag: lane reads row=lane&31,
// k-slice slot (s*2 + lane>>5) ^ ((row>>1)&3).
__global__ __launch_bounds__(512, 2) void conv_kv_kernel(
    const f16_t* __restrict__ y_t, const f16_t* __restrict__ wkv,
    const float* __restrict__ bkv, f16_t* __restrict__ kb,
    f16_t* __restrict__ vb, const char* __restrict__ zp) {
  __shared__ char lds[131072];
  const int tid  = threadIdx.x;
  const int lane = tid & 63;
  const int wid  = tid >> 6;
  const int wr = wid >> 2, wc = wid & 3;   // 2M x 4N

  const int id = blockIdx.x;               // 256 blocks
  const int panel  = id & 7;               // 0..7 (0-3 = k, 4-7 = v)
  const int n_tile = id >> 3;              // 0..31
  const int m0  = panel * 256;             // row in 2048
  const int bn0 = n_tile * 256;
  const int b   = bn0 >> 9;
  const int n0  = bn0 & 511;
  const char* src_c = (const char*)y_t + (size_t)b * NTOK * 2048;
  const char* w_c   = (const char*)wkv;

  const int slotsrc16 = (((tid & 3) ^ ((tid >> 3) & 3)) << 4);
  const int t16 = tid << 4;
  const int r0t = tid >> 2;                // 0..127
  const size_t arow0 = (size_t)(m0 + r0t) * 2048 + slotsrc16;

  int cur_tap = -1;
  const char* bp0 = zp;
  const char* bp1 = zp;

  // 32x32 fragment-read constants
  const int row32  = lane & 31;
  const int kg     = lane >> 5;            // 0..1
  const int swz    = (row32 >> 1) & 3;
  const int sl0    = ((0 + kg) ^ swz) << 4;   // slice 0 slot
  const int sl1    = ((2 + kg) ^ swz) << 4;   // slice 1 slot
  const int rowoff = row32 * 64;

  f32x16 acc[4][2] = {};

  auto stage_half = [&](int tt, int kh, int reg) {   // 4 issues
    const int te = (tt < NKT) ? tt : tt - 2;         // parity-preserving remap
    const int tap = te >> 4, kt = te & 15;
    if (tap != cur_tap) {
      cur_tap = tap;
      const int kd = tap / 9, rem = tap % 9, kh3 = rem / 3, kw3 = rem % 3;
#pragma unroll
      for (int l = 0; l < 2; ++l) {
        const int n = n0 + r0t + l * 128;
        const int d = (n >> 6) + kd - 1;
        const int h = ((n >> 3) & 7) + kh3 - 1;
        const int w = (n & 7) + kw3 - 1;
        const bool ok = ((unsigned)d < 8u) & ((unsigned)h < 8u) & ((unsigned)w < 8u);
        const int nsrc = (d << 6) + (h << 3) + w;
        const char* p = ok ? src_c + (size_t)nsrc * 2048 + slotsrc16 : zp;
        if (l == 0) bp0 = p; else bp1 = p;
      }
    }
    const size_t gA = (size_t)tap * (2048u * 2048u) + (size_t)(kt * 128 + kh * 64);
    char* La = lds + reg;
    gload_lds16(w_c + gA + arow0,                      La + t16);          // A rows 0-127
    gload_lds16(w_c + gA + arow0 + (size_t)128 * 2048, La + 8192 + t16);   // A rows 128-255
    const int ko = kt * 128 + kh * 64;
    gload_lds16(bp0 + ko, La + 16384 + t16);                               // B tok 0-127
    gload_lds16(bp1 + ko, La + 24576 + t16);                               // B tok 128-255
  };

#define KVPHASE(HB, STT, SKH, SREG)                                            \
  {                                                                            \
    const char* A_ = lds + (HB) + wr * 8192 + rowoff;                          \
    const char* B_ = lds + (HB) + 16384 + wc * 4096 + rowoff;                  \
    f16x8 av[4][2], bv[2][2];                                                  \
    _Pragma("unroll") for (int mi = 0; mi < 4; ++mi) {                         \
      av[mi][0] = *(const f16x8*)(A_ + mi * 2048 + sl0);                       \
      av[mi][1] = *(const f16x8*)(A_ + mi * 2048 + sl1);                       \
    }                                                                          \
    _Pragma("unroll") for (int nj = 0; nj < 2; ++nj) {                         \
      bv[nj][0] = *(const f16x8*)(B_ + nj * 2048 + sl0);                       \
      bv[nj][1] = *(const f16x8*)(B_ + nj * 2048 + sl1);                       \
    }                                                                          \
    stage_half((STT), (SKH), (SREG));                                          \
    __builtin_amdgcn_s_setprio(1);                                            \
    _Pragma("unroll") for (int s = 0; s < 2; ++s)                              \
      _Pragma("unroll") for (int mi = 0; mi < 4; ++mi)                         \
        _Pragma("unroll") for (int nj = 0; nj < 2; ++nj)                       \
          acc[mi][nj] = __builtin_amdgcn_mfma_f32_32x32x16_f16(                \
              av[mi][s], bv[nj][s], acc[mi][nj], 0, 0, 0);                     \
    __builtin_amdgcn_s_setprio(0);                                            \
    asm volatile("s_waitcnt vmcnt(8)\n\ts_barrier" ::: "memory");              \
  }

  // prologue: halves (0,0)(0,1)(1,0); wait half0 (keep 8 in flight)
  stage_half(0, 0, 0);
  stage_half(0, 1, 32768);
  stage_half(1, 0, 65536);
  asm volatile("s_waitcnt vmcnt(8)\n\ts_barrier" ::: "memory");

#pragma unroll 1
  for (int t = 0; t < NKT; ++t) {
    const int rb = (t & 1) << 16;
    KVPHASE(rb,         t + 1, 1, (((t + 1) & 1) << 16) + 32768)   // kh0
    KVPHASE(rb + 32768, t + 2, 0, (t & 1) << 16)                   // kh1
  }
#undef KVPHASE

  // epilogue: D col=lane&31 -> token, row=(reg&3)+8*(reg>>2)+4*kg -> channel
  const bool is_k = panel < 4;
#pragma unroll
  for (int mi = 0; mi < 4; ++mi) {
#pragma unroll
    for (int nj = 0; nj < 2; ++nj) {
      const int n = n0 + wc * 64 + nj * 32 + row32;
      if (is_k) {
        f16_t* orow = kb + ((size_t)(b * NTOK + n)) * CCH;
#pragma unroll
        for (int rq = 0; rq < 4; ++rq) {
          const int c0 = m0 + wr * 128 + mi * 32 + rq * 8 + kg * 4;
          const float4 bs = *(const float4*)&bkv[c0];
          f16x4 pk;
          pk[0] = (f16_t)(acc[mi][nj][rq * 4 + 0] + bs.x);
          pk[1] = (f16_t)(acc[mi][nj][rq * 4 + 1] + bs.y);
          pk[2] = (f16_t)(acc[mi][nj][rq * 4 + 2] + bs.z);
          pk[3] = (f16_t)(acc[mi][nj][rq * 4 + 3] + bs.w);
          *(f16x4*)(orow + c0) = pk;
        }
      } else {
#pragma unroll
        for (int rq = 0; rq < 4; ++rq) {
          const int c0 = m0 + wr * 128 + mi * 32 + rq * 8 + kg * 4;
          const float4 bs = *(const float4*)&bkv[c0];
          const float bbv[4] = {bs.x, bs.y, bs.z, bs.w};
#pragma unroll
          for (int q = 0; q < 4; ++q) {
            const int c = c0 - 1024 + q;
            vb[((size_t)b * CCH + c) * NTOK + n] =
                (f16_t)(acc[mi][nj][rq * 4 + q] + bbv[q]);
          }
        }
      }
    }
  }
}

// ================= conv Q: M=1024, tile 256x128, BK=64 =======================
// R6 schedule (4-half 24KB ring, 3 issues/half, counted vmcnt(6)) with
// 32x32x16 MFMA. 8 waves 4Mx2N, wave 64x64 = 2x2 tiles, acc[2][2] f32x16.
__global__ __launch_bounds__(512, 2) void conv_q_kernel(
    const f16_t* __restrict__ x_t, const f16_t* __restrict__ wqt,
    const float* __restrict__ bq, f16_t* __restrict__ qb,
    const char* __restrict__ zp) {
  __shared__ char lds[98304];
  const int tid  = threadIdx.x;
  const int lane = tid & 63;
  const int wid  = tid >> 6;
  const int wr = wid >> 1, wc = wid & 1;   // 4M x 2N

  const int id = blockIdx.x;               // 256 blocks
  const int panel  = id & 3;               // 0..3
  const int n_tile = id >> 2;              // 0..63
  const int m0  = panel * 256;
  const int bn0 = n_tile * 128;
  const int b   = bn0 >> 9;
  const int n0  = bn0 & 511;
  const char* src_c = (const char*)x_t + (size_t)b * NTOK * 2048;
  const char* w_c   = (const char*)wqt;

  const int slotsrc16 = (((tid & 3) ^ ((tid >> 3) & 3)) << 4);
  const int t16 = tid << 4;
  const int r0  = tid >> 2;                // 0..127
  const size_t arow0 = (size_t)(m0 + r0) * 2048 + slotsrc16;

  int cur_tap = -1;
  const char* bp0 = zp;

  const int row32  = lane & 31;
  const int kg     = lane >> 5;
  const int swz    = (row32 >> 1) & 3;
  const int sl0    = ((0 + kg) ^ swz) << 4;
  const int sl1    = ((2 + kg) ^ swz) << 4;
  const int rowoff = row32 * 64;

  f32x16 acc[2][2] = {};

  auto stage_half = [&](int tt, int kh, int reg) {  // 3 issues
    const int te = (tt < NKT) ? tt : tt - 2;
    const int tap = te >> 4, kt = te & 15;
    if (tap != cur_tap) {
      cur_tap = tap;
      const int kd = tap / 9, rem = tap % 9, kh3 = rem / 3, kw3 = rem % 3;
      const int n = n0 + r0;
      const int d = (n >> 6) + kd - 1;
      const int h = ((n >> 3) & 7) + kh3 - 1;
      const int w = (n & 7) + kw3 - 1;
      const bool ok = ((unsigned)d < 8u) & ((unsigned)h < 8u) & ((unsigned)w < 8u);
      const int nsrc = (d << 6) + (h << 3) + w;
      bp0 = ok ? src_c + (size_t)nsrc * 2048 + slotsrc16 : zp;
    }
    const size_t gA = (size_t)tap * (1024u * 2048u) + (size_t)(kt * 128 + kh * 64);
    char* La = lds + reg;
    gload_lds16(w_c + gA + arow0,                      La + t16);
    gload_lds16(w_c + gA + arow0 + (size_t)128 * 2048, La + 8192 + t16);
    gload_lds16(bp0 + kt * 128 + kh * 64,              La + 16384 + t16);
  };

#define QPHASE(HB, STT, SKH, SREG)                                             \
  {                                                                            \
    const char* A_ = lds + (HB) + wr * 4096 + rowoff;                          \
    const char* B_ = lds + (HB) + 16384 + wc * 4096 + rowoff;                  \
    f16x8 av[2][2], bv[2][2];                                                  \
    _Pragma("unroll") for (int mi = 0; mi < 2; ++mi) {                         \
      av[mi][0] = *(const f16x8*)(A_ + mi * 2048 + sl0);                       \
      av[mi][1] = *(const f16x8*)(A_ + mi * 2048 + sl1);                       \
    }                                                                          \
    _Pragma("unroll") for (int nj = 0; nj < 2; ++nj) {                         \
      bv[nj][0] = *(const f16x8*)(B_ + nj * 2048 + sl0);                       \
      bv[nj][1] = *(const f16x8*)(B_ + nj * 2048 + sl1);                       \
    }                                                                          \
    stage_half((STT), (SKH), (SREG));                                          \
    __builtin_amdgcn_s_setprio(1);                                            \
    _Pragma("unroll") for (int s = 0; s < 2; ++s)                              \
      _Pragma("unroll") for (int mi = 0; mi < 2; ++mi)                         \
        _Pragma("unroll") for (int nj = 0; nj < 2; ++nj)                       \
          acc[mi][nj] = __builtin_amdgcn_mfma_f32_32x32x16_f16(                \
              av[mi][s], bv[nj][s], acc[mi][nj], 0, 0, 0);                     \
    __builtin_amdgcn_s_setprio(0);                                            \
    asm volatile("s_waitcnt vmcnt(6)\n\ts_barrier" ::: "memory");              \
  }

  stage_half(0, 0, 0);
  stage_half(0, 1, 24576);
  stage_half(1, 0, 49152);
  asm volatile("s_waitcnt vmcnt(6)\n\ts_barrier" ::: "memory");

#pragma unroll 1
  for (int t = 0; t < NKT; ++t) {
    const int rb = (t & 1) * 49152;
    QPHASE(rb,         t + 1, 1, ((t + 1) & 1) * 49152 + 24576)
    QPHASE(rb + 24576, t + 2, 0, (t & 1) * 49152)
  }
#undef QPHASE

#pragma unroll
  for (int mi = 0; mi < 2; ++mi) {
#pragma unroll
    for (int nj = 0; nj < 2; ++nj) {
      const int n = n0 + wc * 64 + nj * 32 + row32;
      f16_t* orow = qb + ((size_t)(b * NTOK + n)) * CCH;
#pragma unroll
      for (int rq = 0; rq < 4; ++rq) {
        const int c0 = m0 + wr * 64 + mi * 32 + rq * 8 + kg * 4;
        const float4 bs = *(const float4*)&bq[c0];
        f16x4 pk;
        pk[0] = (f16_t)(acc[mi][nj][rq * 4 + 0] + bs.x);
        pk[1] = (f16_t)(acc[mi][nj][rq * 4 + 1] + bs.y);
        pk[2] = (f16_t)(acc[mi][nj][rq * 4 + 2] + bs.z);
        pk[3] = (f16_t)(acc[mi][nj][rq * 4 + 3] + bs.w);
        *(f16x4*)(orow + c0) = pk;
      }
    }
  }
}

// ---------------- generic gemm_bt for attention: C = A * Bt^T (+resid) -------
__global__ __launch_bounds__(256) void attn_gemm_kernel(
    const f16_t* __restrict__ A, const f16_t* __restrict__ Bt,
    float* __restrict__ Cout, const float* __restrict__ resid,
    const int Kdim, const int ldc,
    const size_t strideA, const size_t strideB, const size_t strideC) {
  __shared__ f16_t As[128 * 64];
  __shared__ f16_t Bs[128 * 64];
  char* As_c = (char*)As;
  char* Bs_c = (char*)Bs;

  const int tid  = threadIdx.x;
  const int lane = tid & 63;
  const int wave = tid >> 6;
  const int wr = wave >> 1, wc = wave & 1;
  const int bz = blockIdx.z;
  const int m0 = blockIdx.y * 128;
  const int n0 = blockIdx.x * 128;

  const f16_t* Ab = A + (size_t)bz * strideA;
  const f16_t* Bb = Bt + (size_t)bz * strideB;

  const int rowb = tid >> 3;
  const int colb = (tid & 7) * 16;

  const char* ap[4];
  const char* bp[4];
#pragma unroll
  for (int r = 0; r < 4; ++r) {
    const int row = r * 32 + rowb;
    ap[r] = (const char*)(Ab + (size_t)(m0 + row) * Kdim) + colb;
    bp[r] = (const char*)(Bb + (size_t)(n0 + row) * Kdim) + colb;
  }

  f32x4 acc[4][4] = {};
  const int fr = lane & 15;
  const int fk = (lane >> 4) << 3;

  for (int k0 = 0; k0 < Kdim; k0 += 64) {
#pragma unroll
    for (int r = 0; r < 4; ++r)
      gload_lds16(ap[r], As_c + r * 4096 + wave * 1024);
#pragma unroll
    for (int r = 0; r < 4; ++r)
      gload_lds16(bp[r], Bs_c + r * 4096 + wave * 1024);
#pragma unroll
    for (int r = 0; r < 4; ++r) { ap[r] += 128; bp[r] += 128; }
    __syncthreads();
#pragma unroll
    for (int ks = 0; ks < 2; ++ks) {
      const int kc = ks * 32 + fk;
      f16x8 av[4], bv[4];
#pragma unroll
      for (int i = 0; i < 4; ++i)
        av[i] = *(const f16x8*)&As[(wr * 64 + i * 16 + fr) * 64 + kc];
#pragma unroll
      for (int i = 0; i < 4; ++i)
        bv[i] = *(const f16x8*)&Bs[(wc * 64 + i * 16 + fr) * 64 + kc];
#pragma unroll
      for (int i = 0; i < 4; ++i)
#pragma unroll
        for (int j = 0; j < 4; ++j)
          acc[i][j] = __builtin_amdgcn_mfma_f32_16x16x32_f16(av[i], bv[j], acc[i][j], 0, 0, 0);
    }
    __syncthreads();
  }

  const int mo = m0 + wr * 64 + ((lane >> 4) << 2);
  const int nn = n0 + wc * 64 + (lane & 15);
  float* Cb = Cout + (size_t)bz * strideC;
  const float* Rb = resid ? resid + (size_t)bz * strideC : nullptr;
#pragma unroll
  for (int i = 0; i < 4; ++i) {
#pragma unroll
    for (int j = 0; j < 4; ++j) {
      const int n = nn + j * 16;
#pragma unroll
      for (int reg = 0; reg < 4; ++reg) {
        const int m = mo + i * 16 + reg;
        float v = acc[i][j][reg];
        if (Rb) v += Rb[(size_t)m * ldc + n];
        Cb[(size_t)m * ldc + n] = v;
      }
    }
  }
}

// ---------------- row softmax: S fp32 [rows][512] -> P f16 -------------------
__global__ __launch_bounds__(256) void softmax_kernel(
    const float* __restrict__ S, f16_t* __restrict__ P) {
  const int row  = blockIdx.x * 4 + (threadIdx.x >> 6);
  const int lane = threadIdx.x & 63;
  const float* s = S + (size_t)row * 512;
  const float4 v0 = ((const float4*)s)[lane];
  const float4 v1 = ((const float4*)s)[64 + lane];
  float m = fmaxf(fmaxf(fmaxf(v0.x, v0.y), fmaxf(v0.z, v0.w)),
                  fmaxf(fmaxf(v1.x, v1.y), fmaxf(v1.z, v1.w)));
#pragma unroll
  for (int o = 32; o; o >>= 1) m = fmaxf(m, __shfl_xor(m, o, 64));
  float e[8];
  e[0] = __expf(v0.x - m); e[1] = __expf(v0.y - m);
  e[2] = __expf(v0.z - m); e[3] = __expf(v0.w - m);
  e[4] = __expf(v1.x - m); e[5] = __expf(v1.y - m);
  e[6] = __expf(v1.z - m); e[7] = __expf(v1.w - m);
  float sum = ((e[0] + e[1]) + (e[2] + e[3])) + ((e[4] + e[5]) + (e[6] + e[7]));
#pragma unroll
  for (int o = 32; o; o >>= 1) sum += __shfl_xor(sum, o, 64);
  const float r = 1.0f / sum;
  f16_t* p = P + (size_t)row * 512;
  f16x4 o0, o1;
  o0[0] = (f16_t)(e[0] * r); o0[1] = (f16_t)(e[1] * r);
  o0[2] = (f16_t)(e[2] * r); o0[3] = (f16_t)(e[3] * r);
  o1[0] = (f16_t)(e[4] * r); o1[1] = (f16_t)(e[5] * r);
  o1[2] = (f16_t)(e[6] * r); o1[3] = (f16_t)(e[7] * r);
  ((f16x4*)p)[lane] = o0;
  ((f16x4*)p)[64 + lane] = o1;
}

// -----------------------------------------------------------------------------
extern "C" void kernel_launch(void* const* d_in, const int* in_sizes, int n_in,
                              void* d_out, int out_size, void* d_ws, size_t ws_size,
                              hipStream_t stream) {
  (void)in_sizes; (void)n_in; (void)out_size;
  const float* x  = (const float*)d_in[0];
  const float* y  = (const float*)d_in[1];
  const float* wq = (const float*)d_in[2];
  const float* bq = (const float*)d_in[3];
  const float* wk = (const float*)d_in[4];
  const float* bk = (const float*)d_in[5];
  const float* wv = (const float*)d_in[6];
  const float* bv = (const float*)d_in[7];

  char* ws = (char*)d_ws;
  size_t off = 0;
  auto alloc = [&](size_t bytes) {
    void* p = ws + off;
    off = (off + bytes + 255) & ~(size_t)255;
    return p;
  };
  const size_t act_b = (size_t)BATCH * NTOK * CCH * 2;  // 16 MB
  f16_t* x_t    = (f16_t*)alloc(act_b);
  f16_t* y_t    = (f16_t*)alloc(act_b);
  f16_t* wkv    = (f16_t*)alloc((size_t)27 * 2048 * 1024 * 2);   // 113 MB
  f16_t* wqt    = (f16_t*)alloc((size_t)27 * 1024 * 1024 * 2);   //  57 MB
  float* bkv    = (float*)alloc(2048 * 4);
  f16_t* qb     = (f16_t*)alloc(act_b);
  f16_t* kb     = (f16_t*)alloc(act_b);
  f16_t* vb     = (f16_t*)alloc(act_b);
  float* scores = (float*)alloc((size_t)BATCH * 512 * 512 * 4);  // 16 MB
  f16_t* Pb     = (f16_t*)alloc((size_t)BATCH * 512 * 512 * 2);  //  8 MB
  char*  zerop  = (char*)alloc(4096);
  if (off > ws_size) return;

  const dim3 blk(256);
  hipMemsetAsync(zerop, 0, 4096, stream);
  cast_transpose_kernel<<<dim3(8, 16, 16), blk, 0, stream>>>(x, x_t);
  cast_transpose_kernel<<<dim3(8, 16, 16), blk, 0, stream>>>(y, y_t);

  wtrans_kernel<<<dim3(1024, 16), blk, 0, stream>>>(wk, wkv, 0, 2048);
  wtrans_kernel<<<dim3(1024, 16), blk, 0, stream>>>(wv, wkv, 1024, 2048);
  wtrans_kernel<<<dim3(1024, 16), blk, 0, stream>>>(wq, wqt, 0, 1024);
  hipMemcpyAsync(bkv,        bk, 1024 * 4, hipMemcpyDeviceToDevice, stream);
  hipMemcpyAsync(bkv + 1024, bv, 1024 * 4, hipMemcpyDeviceToDevice, stream);

  conv_kv_kernel<<<dim3(256), dim3(512), 0, stream>>>(y_t, wkv, bkv, kb, vb, zerop);
  conv_q_kernel<<<dim3(256), dim3(512), 0, stream>>>(x_t, wqt, bq, qb, zerop);

  // scores[b][n][m] = sum_c q[b][n][c] * k[b][m][c]
  attn_gemm_kernel<<<dim3(4, 4, 16), blk, 0, stream>>>(
      qb, kb, scores, nullptr, 1024, 512,
      (size_t)512 * 1024, (size_t)512 * 1024, (size_t)512 * 512);
  softmax_kernel<<<dim3(BATCH * 512 / 4), blk, 0, stream>>>(scores, Pb);
  // out[b][c][n] = sum_m v[b][c][m] * P[b][n][m] + x[b][c][n]
  attn_gemm_kernel<<<dim3(4, 8, 16), blk, 0, stream>>>(
      vb, Pb, (float*)d_out, x, 512, 512,
      (size_t)1024 * 512, (size_t)512 * 512, (size_t)1024 * 512);
}

// Round 11
// 1422.137 us; speedup vs baseline: 1.1131x; 1.1131x over previous
//
#include <hip/hip_runtime.h>
#include <hip/hip_bf16.h>
#include <stdint.h>

// B=16, C=1024, D=H=W=8 -> N=512 tokens, 27 taps
#define BATCH 16
#define CCH   1024
#define NTOK  512
#define NKT   432   // K-tiles: 27 taps * (1024/64)

typedef _Float16 f16_t;
typedef f16_t f16x8 __attribute__((ext_vector_type(8)));
typedef f16_t f16x4 __attribute__((ext_vector_type(4)));
typedef float f32x4 __attribute__((ext_vector_type(4)));

#define GAS __attribute__((address_space(1)))
#define LAS __attribute__((address_space(3)))

__device__ __forceinline__ void gload_lds16(const void* g, void* l) {
  __builtin_amdgcn_global_load_lds((const GAS uint32_t*)g, (LAS uint32_t*)l, 16, 0, 0);
}

// ---------------- cast + transpose: [B][C][N] f32 -> [B][N][C] f16 -----------
__global__ __launch_bounds__(256) void cast_transpose_kernel(
    const float* __restrict__ src, f16_t* __restrict__ dst) {
  __shared__ float tile[64][65];
  const int b  = blockIdx.z;
  const int c0 = blockIdx.y * 64;
  const int n0 = blockIdx.x * 64;
  const int col  = threadIdx.x & 63;
  const int row4 = threadIdx.x >> 6;
  const float* s = src + ((size_t)b * CCH + c0) * NTOK + n0;
#pragma unroll
  for (int r = 0; r < 64; r += 4)
    tile[r + row4][col] = s[(size_t)(r + row4) * NTOK + col];
  __syncthreads();
  f16_t* d = dst + ((size_t)b * NTOK + n0) * CCH + c0;
#pragma unroll
  for (int r = 0; r < 64; r += 4)
    d[(size_t)(r + row4) * CCH + col] = (f16_t)tile[col][r + row4];
}

// -------- weight transpose: [O][I][27] f32 -> rows o_base+o of [27][Mtot][1024]
__global__ __launch_bounds__(256) void wtrans_kernel(
    const float* __restrict__ w, f16_t* __restrict__ wt, const int o_base,
    const int Mtot) {
  __shared__ float buf[64 * 27];
  const int o  = blockIdx.x;
  const int i0 = blockIdx.y * 64;
  const float* s = w + (size_t)o * (CCH * 27) + (size_t)i0 * 27;
  for (int idx = threadIdx.x; idx < 64 * 27; idx += 256) buf[idx] = s[idx];
  __syncthreads();
  for (int idx = threadIdx.x; idx < 64 * 27; idx += 256) {
    const int t = idx >> 6;
    const int i = idx & 63;
    wt[((size_t)t * Mtot + o_base + o) * 1024 + i0 + i] = (f16_t)buf[i * 27 + t];
  }
}

// ================= conv K+V fused: M=2048, tile 256x256, BK=64 ===============
// 256 blocks (8 m-panels x 32 n-tiles), 512 thr = 8 waves (2M x 4N),
// wave tile 128x64, acc 8x4. K-tile split into 2 kh-halves of 32KB
// (A 16K + B 16K); 4-half ring (128KB). Per phase: ds_read 12 frags ->
// stage half h+2 (4 uniform issues) -> setprio+32 MFMA ->
// counted vmcnt(8)+barrier (keeps 2 halves in flight across every barrier;
// issue-to-wait ~2 phases covers HBM latency). Source-side slot swizzle
// slot^((row>>1)&3); fragment reads land 2 lanes/bank (free).
__global__ __launch_bounds__(512, 2) void conv_kv_kernel(
    const f16_t* __restrict__ y_t, const f16_t* __restrict__ wkv,
    const float* __restrict__ bkv, f16_t* __restrict__ kb,
    f16_t* __restrict__ vb, const char* __restrict__ zp) {
  __shared__ char lds[131072];
  const int tid  = threadIdx.x;
  const int lane = tid & 63;
  const int wid  = tid >> 6;
  const int wr = wid >> 2, wc = wid & 3;   // 2M x 4N

  const int id = blockIdx.x;               // 256 blocks
  const int panel  = id & 7;               // 0..7 (0-3 = k, 4-7 = v)
  const int n_tile = id >> 3;              // 0..31
  const int m0  = panel * 256;             // row in 2048
  const int bn0 = n_tile * 256;
  const int b   = bn0 >> 9;
  const int n0  = bn0 & 511;
  const char* src_c = (const char*)y_t + (size_t)b * NTOK * 2048;
  const char* w_c   = (const char*)wkv;

  const int slotsrc16 = (((tid & 3) ^ ((tid >> 3) & 3)) << 4);
  const int t16 = tid << 4;
  const int r0t = tid >> 2;                // 0..127
  const size_t arow0 = (size_t)(m0 + r0t) * 2048 + slotsrc16;

  int cur_tap = -1;
  const char* bp0 = zp;
  const char* bp1 = zp;

  const int fr = lane & 15;
  const int rdbase = fr * 64 + (((lane >> 4) ^ ((fr >> 1) & 3)) << 4);

  f32x4 acc[8][4] = {};

  // stage one kh-half (4 issues) of K-tile tt into ring region `reg`
  auto stage_half = [&](int tt, int kh, int reg) {
    const int te = (tt < NKT) ? tt : tt - 2;   // parity-preserving tail remap
    const int tap = te >> 4, kt = te & 15;
    if (tap != cur_tap) {
      cur_tap = tap;
      const int kd = tap / 9, rem = tap % 9, kh3 = rem / 3, kw3 = rem % 3;
#pragma unroll
      for (int l = 0; l < 2; ++l) {
        const int n = n0 + r0t + l * 128;
        const int d = (n >> 6) + kd - 1;
        const int h = ((n >> 3) & 7) + kh3 - 1;
        const int w = (n & 7) + kw3 - 1;
        const bool ok = ((unsigned)d < 8u) & ((unsigned)h < 8u) & ((unsigned)w < 8u);
        const int nsrc = (d << 6) + (h << 3) + w;
        const char* p = ok ? src_c + (size_t)nsrc * 2048 + slotsrc16 : zp;
        if (l == 0) bp0 = p; else bp1 = p;
      }
    }
    const size_t gA = (size_t)tap * (2048u * 2048u) + (size_t)(kt * 128 + kh * 64);
    char* La = lds + reg;
    gload_lds16(w_c + gA + arow0,                      La + t16);          // A rows 0-127
    gload_lds16(w_c + gA + arow0 + (size_t)128 * 2048, La + 8192 + t16);   // A rows 128-255
    const int ko = kt * 128 + kh * 64;
    gload_lds16(bp0 + ko, La + 16384 + t16);                               // B tok 0-127
    gload_lds16(bp1 + ko, La + 24576 + t16);                               // B tok 128-255
  };

#define MFMA32(AV, BV)                                                         \
  _Pragma("unroll") for (int i = 0; i < 8; ++i) {                              \
    _Pragma("unroll") for (int j = 0; j < 4; ++j)                              \
        acc[i][j] = __builtin_amdgcn_mfma_f32_16x16x32_f16(                    \
            AV[i], BV[j], acc[i][j], 0, 0, 0);                                 \
  }

  // prologue: halves (0,0)(0,1)(1,0); wait half0 (keep 8 in flight)
  stage_half(0, 0, 0);
  stage_half(0, 1, 32768);
  stage_half(1, 0, 65536);
  asm volatile("s_waitcnt vmcnt(8)\n\ts_barrier" ::: "memory");

#pragma unroll 1
  for (int t = 0; t < NKT; ++t) {
    const int rb = (t & 1) << 16;
    // ---- phase kh0
    {
      const char* sA = lds + rb + wr * 8192 + rdbase;
      const char* sB = lds + rb + 16384 + wc * 4096 + rdbase;
      f16x8 av[8], bv[4];
#pragma unroll
      for (int j = 0; j < 4; ++j) bv[j] = *(const f16x8*)(sB + j * 1024);
#pragma unroll
      for (int i = 0; i < 8; ++i) av[i] = *(const f16x8*)(sA + i * 1024);
      stage_half(t + 1, 1, (((t + 1) & 1) << 16) + 32768);
      __builtin_amdgcn_s_setprio(1);
      MFMA32(av, bv)
      __builtin_amdgcn_s_setprio(0);
      asm volatile("s_waitcnt vmcnt(8)\n\ts_barrier" ::: "memory");
    }
    // ---- phase kh1
    {
      const char* sA = lds + rb + 32768 + wr * 8192 + rdbase;
      const char* sB = lds + rb + 32768 + 16384 + wc * 4096 + rdbase;
      f16x8 av[8], bv[4];
#pragma unroll
      for (int j = 0; j < 4; ++j) bv[j] = *(const f16x8*)(sB + j * 1024);
#pragma unroll
      for (int i = 0; i < 8; ++i) av[i] = *(const f16x8*)(sA + i * 1024);
      stage_half(t + 2, 0, (t & 1) << 16);
      __builtin_amdgcn_s_setprio(1);
      MFMA32(av, bv)
      __builtin_amdgcn_s_setprio(0);
      asm volatile("s_waitcnt vmcnt(8)\n\ts_barrier" ::: "memory");
    }
  }
#undef MFMA32

  // epilogue: C col=lane&15 -> token, row=(lane>>4)*4+reg -> channel
  const int rq = (lane >> 4) << 2;
  const bool is_k = panel < 4;
#pragma unroll
  for (int i = 0; i < 8; ++i) {
    const int c = m0 + wr * 128 + i * 16 + rq;       // 0..2047
    const float4 bs = *(const float4*)&bkv[c];
    if (is_k) {
#pragma unroll
      for (int j = 0; j < 4; ++j) {
        const int n = n0 + wc * 64 + j * 16 + fr;
        f16x4 pk;
        pk[0] = (f16_t)(acc[i][j][0] + bs.x);
        pk[1] = (f16_t)(acc[i][j][1] + bs.y);
        pk[2] = (f16_t)(acc[i][j][2] + bs.z);
        pk[3] = (f16_t)(acc[i][j][3] + bs.w);
        *(f16x4*)(kb + ((size_t)(b * NTOK + n)) * CCH + c) = pk;
      }
    } else {
      const int cc = c - 1024;
      const float bbv[4] = {bs.x, bs.y, bs.z, bs.w};
#pragma unroll
      for (int reg = 0; reg < 4; ++reg) {
        f16_t* dst = vb + ((size_t)b * CCH + cc + reg) * NTOK;
#pragma unroll
        for (int j = 0; j < 4; ++j) {
          const int n = n0 + wc * 64 + j * 16 + fr;
          dst[n] = (f16_t)(acc[i][j][reg] + bbv[reg]);
        }
      }
    }
  }
}

// ================= conv Q: M=1024, tile 256x128, BK=64 =======================
// 256 blocks (4 panels x 64 n-tiles), 8 waves (4M x 2N), wave 64x64, acc 4x4.
// kh-half = 24KB, 4-half ring (96KB), 3 loads/half, counted vmcnt(6).
__global__ __launch_bounds__(512, 2) void conv_q_kernel(
    const f16_t* __restrict__ x_t, const f16_t* __restrict__ wqt,
    const float* __restrict__ bq, f16_t* __restrict__ qb,
    const char* __restrict__ zp) {
  __shared__ char lds[98304];
  const int tid  = threadIdx.x;
  const int lane = tid & 63;
  const int wid  = tid >> 6;
  const int wr = wid >> 1, wc = wid & 1;   // 4M x 2N

  const int id = blockIdx.x;               // 256 blocks
  const int panel  = id & 3;               // 0..3
  const int n_tile = id >> 2;              // 0..63
  const int m0  = panel * 256;
  const int bn0 = n_tile * 128;
  const int b   = bn0 >> 9;
  const int n0  = bn0 & 511;
  const char* src_c = (const char*)x_t + (size_t)b * NTOK * 2048;
  const char* w_c   = (const char*)wqt;

  const int slotsrc16 = (((tid & 3) ^ ((tid >> 3) & 3)) << 4);
  const int t16 = tid << 4;
  const int r0  = tid >> 2;
  const size_t arow0 = (size_t)(m0 + r0) * 2048 + slotsrc16;

  int cur_tap = -1;
  const char* bp0 = zp;

  const int fr = lane & 15;
  const int rdbase = fr * 64 + (((lane >> 4) ^ ((fr >> 1) & 3)) << 4);

  f32x4 acc[4][4] = {};

  auto upd_tap = [&](int tap) {
    cur_tap = tap;
    const int kd = tap / 9, rem = tap % 9, kh = rem / 3, kw = rem % 3;
    const int n = n0 + r0;
    const int d = (n >> 6) + kd - 1;
    const int h = ((n >> 3) & 7) + kh - 1;
    const int w = (n & 7) + kw - 1;
    const bool ok = ((unsigned)d < 8u) & ((unsigned)h < 8u) & ((unsigned)w < 8u);
    const int nsrc = (d << 6) + (h << 3) + w;
    bp0 = ok ? src_c + (size_t)nsrc * 2048 + slotsrc16 : zp;
  };
  auto stage_half = [&](int tt, int kh, int reg) {  // 3 loads
    const int te = (tt < NKT) ? tt : tt - 2;
    const int tap = te >> 4, kt = te & 15;
    if (tap != cur_tap) upd_tap(tap);
    const size_t gA = (size_t)tap * (1024u * 2048u) + (size_t)(kt * 128 + kh * 64);
    char* La = lds + reg;
    gload_lds16(w_c + gA + arow0,                      La + t16);
    gload_lds16(w_c + gA + arow0 + (size_t)128 * 2048, La + 8192 + t16);
    gload_lds16(bp0 + kt * 128 + kh * 64,              La + 16384 + t16);
  };

#define MFMA16Q(AV, BV)                                                        \
  _Pragma("unroll") for (int i = 0; i < 4; ++i) {                              \
    _Pragma("unroll") for (int j = 0; j < 4; ++j)                              \
        acc[i][j] = __builtin_amdgcn_mfma_f32_16x16x32_f16(                    \
            AV[i], BV[j], acc[i][j], 0, 0, 0);                                 \
  }

  stage_half(0, 0, 0);
  stage_half(0, 1, 24576);
  stage_half(1, 0, 49152);
  asm volatile("s_waitcnt vmcnt(6)\n\ts_barrier" ::: "memory");

#pragma unroll 1
  for (int t = 0; t < NKT; ++t) {
    const int rb = (t & 1) * 49152;               // region: tile t, kh0
    {
      const char* sA = lds + rb + wr * 4096 + rdbase;
      const char* sB = lds + rb + 16384 + wc * 4096 + rdbase;
      f16x8 av[4], bv[4];
#pragma unroll
      for (int j = 0; j < 4; ++j) bv[j] = *(const f16x8*)(sB + j * 1024);
#pragma unroll
      for (int i = 0; i < 4; ++i) av[i] = *(const f16x8*)(sA + i * 1024);
      stage_half(t + 1, 1, ((t + 1) & 1) * 49152 + 24576);
      __builtin_amdgcn_s_setprio(1);
      MFMA16Q(av, bv)
      __builtin_amdgcn_s_setprio(0);
      asm volatile("s_waitcnt vmcnt(6)\n\ts_barrier" ::: "memory");
    }
    {
      const char* sA = lds + rb + 24576 + wr * 4096 + rdbase;
      const char* sB = lds + rb + 24576 + 16384 + wc * 4096 + rdbase;
      f16x8 av[4], bv[4];
#pragma unroll
      for (int j = 0; j < 4; ++j) bv[j] = *(const f16x8*)(sB + j * 1024);
#pragma unroll
      for (int i = 0; i < 4; ++i) av[i] = *(const f16x8*)(sA + i * 1024);
      stage_half(t + 2, 0, (t & 1) * 49152);
      __builtin_amdgcn_s_setprio(1);
      MFMA16Q(av, bv)
      __builtin_amdgcn_s_setprio(0);
      asm volatile("s_waitcnt vmcnt(6)\n\ts_barrier" ::: "memory");
    }
  }
#undef MFMA16Q

  const int rq = (lane >> 4) << 2;
#pragma unroll
  for (int i = 0; i < 4; ++i) {
    const int c = m0 + wr * 64 + i * 16 + rq;        // 0..1023
    const float4 bs = *(const float4*)&bq[c];
#pragma unroll
    for (int j = 0; j < 4; ++j) {
      const int n = n0 + wc * 64 + j * 16 + fr;
      f16x4 pk;
      pk[0] = (f16_t)(acc[i][j][0] + bs.x);
      pk[1] = (f16_t)(acc[i][j][1] + bs.y);
      pk[2] = (f16_t)(acc[i][j][2] + bs.z);
      pk[3] = (f16_t)(acc[i][j][3] + bs.w);
      *(f16x4*)(qb + ((size_t)(b * NTOK + n)) * CCH + c) = pk;
    }
  }
}

// ---------------- generic gemm_bt for attention: C = A * Bt^T (+resid) -------
__global__ __launch_bounds__(256) void attn_gemm_kernel(
    const f16_t* __restrict__ A, const f16_t* __restrict__ Bt,
    float* __restrict__ Cout, const float* __restrict__ resid,
    const int Kdim, const int ldc,
    const size_t strideA, const size_t strideB, const size_t strideC) {
  __shared__ f16_t As[128 * 64];
  __shared__ f16_t Bs[128 * 64];
  char* As_c = (char*)As;
  char* Bs_c = (char*)Bs;

  const int tid  = threadIdx.x;
  const int lane = tid & 63;
  const int wave = tid >> 6;
  const int wr = wave >> 1, wc = wave & 1;
  const int bz = blockIdx.z;
  const int m0 = blockIdx.y * 128;
  const int n0 = blockIdx.x * 128;

  const f16_t* Ab = A + (size_t)bz * strideA;
  const f16_t* Bb = Bt + (size_t)bz * strideB;

  const int rowb = tid >> 3;
  const int colb = (tid & 7) * 16;

  const char* ap[4];
  const char* bp[4];
#pragma unroll
  for (int r = 0; r < 4; ++r) {
    const int row = r * 32 + rowb;
    ap[r] = (const char*)(Ab + (size_t)(m0 + row) * Kdim) + colb;
    bp[r] = (const char*)(Bb + (size_t)(n0 + row) * Kdim) + colb;
  }

  f32x4 acc[4][4] = {};
  const int fr = lane & 15;
  const int fk = (lane >> 4) << 3;

  for (int k0 = 0; k0 < Kdim; k0 += 64) {
#pragma unroll
    for (int r = 0; r < 4; ++r)
      gload_lds16(ap[r], As_c + r * 4096 + wave * 1024);
#pragma unroll
    for (int r = 0; r < 4; ++r)
      gload_lds16(bp[r], Bs_c + r * 4096 + wave * 1024);
#pragma unroll
    for (int r = 0; r < 4; ++r) { ap[r] += 128; bp[r] += 128; }
    __syncthreads();
#pragma unroll
    for (int ks = 0; ks < 2; ++ks) {
      const int kc = ks * 32 + fk;
      f16x8 av[4], bv[4];
#pragma unroll
      for (int i = 0; i < 4; ++i)
        av[i] = *(const f16x8*)&As[(wr * 64 + i * 16 + fr) * 64 + kc];
#pragma unroll
      for (int i = 0; i < 4; ++i)
        bv[i] = *(const f16x8*)&Bs[(wc * 64 + i * 16 + fr) * 64 + kc];
#pragma unroll
      for (int i = 0; i < 4; ++i)
#pragma unroll
        for (int j = 0; j < 4; ++j)
          acc[i][j] = __builtin_amdgcn_mfma_f32_16x16x32_f16(av[i], bv[j], acc[i][j], 0, 0, 0);
    }
    __syncthreads();
  }

  const int mo = m0 + wr * 64 + ((lane >> 4) << 2);
  const int nn = n0 + wc * 64 + (lane & 15);
  float* Cb = Cout + (size_t)bz * strideC;
  const float* Rb = resid ? resid + (size_t)bz * strideC : nullptr;
#pragma unroll
  for (int i = 0; i < 4; ++i) {
#pragma unroll
    for (int j = 0; j < 4; ++j) {
      const int n = nn + j * 16;
#pragma unroll
      for (int reg = 0; reg < 4; ++reg) {
        const int m = mo + i * 16 + reg;
        float v = acc[i][j][reg];
        if (Rb) v += Rb[(size_t)m * ldc + n];
        Cb[(size_t)m * ldc + n] = v;
      }
    }
  }
}

// ---------------- row softmax: S fp32 [rows][512] -> P f16 -------------------
__global__ __launch_bounds__(256) void softmax_kernel(
    const float* __restrict__ S, f16_t* __restrict__ P) {
  const int row  = blockIdx.x * 4 + (threadIdx.x >> 6);
  const int lane = threadIdx.x & 63;
  const float* s = S + (size_t)row * 512;
  const float4 v0 = ((const float4*)s)[lane];
  const float4 v1 = ((const float4*)s)[64 + lane];
  float m = fmaxf(fmaxf(fmaxf(v0.x, v0.y), fmaxf(v0.z, v0.w)),
                  fmaxf(fmaxf(v1.x, v1.y), fmaxf(v1.z, v1.w)));
#pragma unroll
  for (int o = 32; o; o >>= 1) m = fmaxf(m, __shfl_xor(m, o, 64));
  float e[8];
  e[0] = __expf(v0.x - m); e[1] = __expf(v0.y - m);
  e[2] = __expf(v0.z - m); e[3] = __expf(v0.w - m);
  e[4] = __expf(v1.x - m); e[5] = __expf(v1.y - m);
  e[6] = __expf(v1.z - m); e[7] = __expf(v1.w - m);
  float sum = ((e[0] + e[1]) + (e[2] + e[3])) + ((e[4] + e[5]) + (e[6] + e[7]));
#pragma unroll
  for (int o = 32; o; o >>= 1) sum += __shfl_xor(sum, o, 64);
  const float r = 1.0f / sum;
  f16_t* p = P + (size_t)row * 512;
  f16x4 o0, o1;
  o0[0] = (f16_t)(e[0] * r); o0[1] = (f16_t)(e[1] * r);
  o0[2] = (f16_t)(e[2] * r); o0[3] = (f16_t)(e[3] * r);
  o1[0] = (f16_t)(e[4] * r); o1[1] = (f16_t)(e[5] * r);
  o1[2] = (f16_t)(e[6] * r); o1[3] = (f16_t)(e[7] * r);
  ((f16x4*)p)[lane] = o0;
  ((f16x4*)p)[64 + lane] = o1;
}

// -----------------------------------------------------------------------------
extern "C" void kernel_launch(void* const* d_in, const int* in_sizes, int n_in,
                              void* d_out, int out_size, void* d_ws, size_t ws_size,
                              hipStream_t stream) {
  (void)in_sizes; (void)n_in; (void)out_size;
  const float* x  = (const float*)d_in[0];
  const float* y  = (const float*)d_in[1];
  const float* wq = (const float*)d_in[2];
  const float* bq = (const float*)d_in[3];
  const float* wk = (const float*)d_in[4];
  const float* bk = (const float*)d_in[5];
  const float* wv = (const float*)d_in[6];
  const float* bv = (const float*)d_in[7];

  char* ws = (char*)d_ws;
  size_t off = 0;
  auto alloc = [&](size_t bytes) {
    void* p = ws + off;
    off = (off + bytes + 255) & ~(size_t)255;
    return p;
  };
  const size_t act_b = (size_t)BATCH * NTOK * CCH * 2;  // 16 MB
  f16_t* x_t    = (f16_t*)alloc(act_b);
  f16_t* y_t    = (f16_t*)alloc(act_b);
  f16_t* wkv    = (f16_t*)alloc((size_t)27 * 2048 * 1024 * 2);   // 113 MB
  f16_t* wqt    = (f16_t*)alloc((size_t)27 * 1024 * 1024 * 2);   //  57 MB
  float* bkv    = (float*)alloc(2048 * 4);
  f16_t* qb     = (f16_t*)alloc(act_b);
  f16_t* kb     = (f16_t*)alloc(act_b);
  f16_t* vb     = (f16_t*)alloc(act_b);
  float* scores = (float*)alloc((size_t)BATCH * 512 * 512 * 4);  // 16 MB
  f16_t* Pb     = (f16_t*)alloc((size_t)BATCH * 512 * 512 * 2);  //  8 MB
  char*  zerop  = (char*)alloc(4096);
  if (off > ws_size) return;

  const dim3 blk(256);
  hipMemsetAsync(zerop, 0, 4096, stream);
  cast_transpose_kernel<<<dim3(8, 16, 16), blk, 0, stream>>>(x, x_t);
  cast_transpose_kernel<<<dim3(8, 16, 16), blk, 0, stream>>>(y, y_t);

  wtrans_kernel<<<dim3(1024, 16), blk, 0, stream>>>(wk, wkv, 0, 2048);
  wtrans_kernel<<<dim3(1024, 16), blk, 0, stream>>>(wv, wkv, 1024, 2048);
  wtrans_kernel<<<dim3(1024, 16), blk, 0, stream>>>(wq, wqt, 0, 1024);
  hipMemcpyAsync(bkv,        bk, 1024 * 4, hipMemcpyDeviceToDevice, stream);
  hipMemcpyAsync(bkv + 1024, bv, 1024 * 4, hipMemcpyDeviceToDevice, stream);

  conv_kv_kernel<<<dim3(256), dim3(512), 0, stream>>>(y_t, wkv, bkv, kb, vb, zerop);
  conv_q_kernel<<<dim3(256), dim3(512), 0, stream>>>(x_t, wqt, bq, qb, zerop);

  // scores[b][n][m] = sum_c q[b][n][c] * k[b][m][c]
  attn_gemm_kernel<<<dim3(4, 4, 16), blk, 0, stream>>>(
      qb, kb, scores, nullptr, 1024, 512,
      (size_t)512 * 1024, (size_t)512 * 1024, (size_t)512 * 512);
  softmax_kernel<<<dim3(BATCH * 512 / 4), blk, 0, stream>>>(scores, Pb);
  // out[b][c][n] = sum_m v[b][c][m] * P[b][n][m] + x[b][c][n]
  attn_gemm_kernel<<<dim3(4, 8, 16), blk, 0, stream>>>(
      vb, Pb, (float*)d_out, x, 512, 512,
      (size_t)1024 * 512, (size_t)512 * 512, (size_t)1024 * 512);
}